// Round 1
// baseline (1398.231 us; speedup 1.0000x reference)
//
#include <hip/hip_runtime.h>
#include <hip/hip_bf16.h>
#include <stdint.h>

#define N_NODES   50000
#define N_EDGES   400000
#define NK        100000
#define C_CL      25000
#define TOTE      12800000            // N * 16 * 16 pair slots
#define BM_WORDS  19531250            // C*C / 32  (exact)
#define BM_WPB    4096                // bitmap words per scan block
#define BM_NB     4769                // ceil(BM_WORDS / BM_WPB)
#define BM_WORDS_PAD (BM_NB * BM_WPB)

// ---------------- generic 128-K matmul: out[r][c] = sum_k A[r][k] * B[k][bcol0+c], c<128
__global__ __launch_bounds__(256) void mm128(const float* __restrict__ A, int lda,
                                             const float* __restrict__ B, int ldb, int bcol0,
                                             float* __restrict__ out, int rows) {
    int t = blockIdx.x * 256 + threadIdx.x;
    int r = t >> 5;
    int c = (t & 31) << 2;
    if (r >= rows) return;
    const float* Ar = A + (size_t)r * lda;
    const float* Bc = B + bcol0 + c;
    float4 acc = make_float4(0.f, 0.f, 0.f, 0.f);
#pragma unroll
    for (int k = 0; k < 128; k += 4) {
        float4 a  = *(const float4*)(Ar + k);
        float4 b0 = *(const float4*)(Bc + (size_t)(k + 0) * ldb);
        float4 b1 = *(const float4*)(Bc + (size_t)(k + 1) * ldb);
        float4 b2 = *(const float4*)(Bc + (size_t)(k + 2) * ldb);
        float4 b3 = *(const float4*)(Bc + (size_t)(k + 3) * ldb);
        acc.x += a.x * b0.x + a.y * b1.x + a.z * b2.x + a.w * b3.x;
        acc.y += a.x * b0.y + a.y * b1.y + a.z * b2.y + a.w * b3.y;
        acc.z += a.x * b0.z + a.y * b1.z + a.z * b2.z + a.w * b3.z;
        acc.w += a.x * b0.w + a.y * b1.w + a.z * b2.w + a.w * b3.w;
    }
    *(float4*)(out + (size_t)r * 128 + c) = acc;
}

// ---------------- histograms
__global__ __launch_bounds__(256) void hist_idx(const int* __restrict__ idx, int n, int* __restrict__ cnt) {
    int i = blockIdx.x * 256 + threadIdx.x;
    if (i < n) atomicAdd(&cnt[idx[i]], 1);
}

// ---------------- per-block sum (256 elems/block)
__global__ __launch_bounds__(256) void reduce_blk(const int* __restrict__ v, int n, int* __restrict__ bsum) {
    __shared__ int s[256];
    int t = threadIdx.x;
    int i = blockIdx.x * 256 + t;
    s[t] = (i < n) ? v[i] : 0;
    __syncthreads();
    for (int o = 128; o > 0; o >>= 1) { if (t < o) s[t] += s[t + o]; __syncthreads(); }
    if (t == 0) bsum[blockIdx.x] = s[0];
}

// ---------------- single-block exclusive scan (in place), optional grand total out
__global__ __launch_bounds__(256) void scan_small(int* data, int n, int* total_out) {
    __shared__ int s[256];
    __shared__ int carry;
    int t = threadIdx.x;
    if (t == 0) carry = 0;
    __syncthreads();
    for (int base = 0; base < n; base += 256) {
        int i = base + t;
        int v = (i < n) ? data[i] : 0;
        s[t] = v;
        __syncthreads();
        for (int o = 1; o < 256; o <<= 1) {
            int x = (t >= o) ? s[t - o] : 0;
            __syncthreads();
            s[t] += x;
            __syncthreads();
        }
        int inc = s[t];
        int tot = s[255];
        int cy  = carry;
        __syncthreads();
        if (i < n) data[i] = cy + inc - v;   // exclusive
        if (t == 0) carry = cy + tot;
        __syncthreads();
    }
    if (t == 0 && total_out) *total_out = carry;
}

// ---------------- final exclusive offsets: offs[i] = bscan[blk] + local exclusive prefix
__global__ __launch_bounds__(256) void scan_offs(const int* __restrict__ cnt, int n,
                                                 const int* __restrict__ bscan, int* __restrict__ offs) {
    __shared__ int s[256];
    int t = threadIdx.x;
    int i = blockIdx.x * 256 + t;
    int v = (i < n) ? cnt[i] : 0;
    s[t] = v;
    __syncthreads();
    for (int o = 1; o < 256; o <<= 1) {
        int x = (t >= o) ? s[t - o] : 0;
        __syncthreads();
        s[t] += x;
        __syncthreads();
    }
    if (i < n) offs[i] = bscan[blockIdx.x] + s[t] - v;
}

// ---------------- scatter indices into CSR lists
__global__ __launch_bounds__(256) void scatter_ids(const int* __restrict__ idx, int n,
                                                   int* __restrict__ cursors, int* __restrict__ ids) {
    int i = blockIdx.x * 256 + threadIdx.x;
    if (i < n) {
        int p = atomicAdd(&cursors[idx[i]], 1);
        ids[p] = i;
    }
}

// ---------------- per-dst-node gather: h[n] = (sum y[src] + (sum ea) @ Wce[:,16:]) / max(cnt,1)
__global__ __launch_bounds__(256) void gather_h(const float* __restrict__ y, const float* __restrict__ ea,
                                                const int* __restrict__ offs, const int* __restrict__ cnt,
                                                const int* __restrict__ eids, const float* __restrict__ Wce,
                                                float* __restrict__ h) {
    int l = threadIdx.x & 63;
    int n = blockIdx.x * 4 + (threadIdx.x >> 6);
    int off = offs[n], m = cnt[n];
    float ax = 0.f, ay = 0.f, ae = 0.f;
    for (int i = 0; i < m; ++i) {
        int e = eids[off + i];
        int s = e >> 3;                                   // src = e / DEG
        float2 v = *(const float2*)(y + (size_t)s * 128 + 2 * l);
        ax += v.x; ay += v.y;
        if (l < 3) ae += ea[(size_t)e * 3 + l];
    }
    float e0 = __shfl(ae, 0), e1 = __shfl(ae, 1), e2 = __shfl(ae, 2);
    float inv = 1.f / (float)(m > 0 ? m : 1);
    int c0 = 2 * l, c1 = 2 * l + 1;
    float h0 = (ax + e0 * Wce[16 + c0] + e1 * Wce[144 + 16 + c0] + e2 * Wce[288 + 16 + c0]) * inv;
    float h1 = (ay + e0 * Wce[16 + c1] + e1 * Wce[144 + 16 + c1] + e2 * Wce[288 + 16 + c1]) * inv;
    *(float2*)(h + (size_t)n * 128 + 2 * l) = make_float2(h0, h1);
}

// ---------------- per-cluster gather: x_new[c] = sum hW[b>>1]/max(cnt,1); new_pos[c] = sum pos[b>>1]/max(cnt,1)
__global__ __launch_bounds__(256) void gather_out(const float* __restrict__ hW, const float* __restrict__ pos,
                                                  const int* __restrict__ offs2, const int* __restrict__ cnt2,
                                                  const int* __restrict__ bids,
                                                  float* __restrict__ xnew, float* __restrict__ newpos) {
    int l = threadIdx.x & 63;
    int c = blockIdx.x * 4 + (threadIdx.x >> 6);
    int off = offs2[c], m = cnt2[c];
    float ax = 0.f, ay = 0.f, ap = 0.f;
    for (int i = 0; i < m; ++i) {
        int b  = bids[off + i];
        int nd = b >> 1;
        float2 v = *(const float2*)(hW + (size_t)nd * 128 + 2 * l);
        ax += v.x; ay += v.y;
        if (l < 3) ap += pos[(size_t)nd * 3 + l];
    }
    float inv = 1.f / (float)(m > 0 ? m : 1);
    *(float2*)(xnew + (size_t)c * 128 + 2 * l) = make_float2(ax * inv, ay * inv);
    if (l < 3) newpos[(size_t)c * 3 + l] = ap * inv;
}

// ---------------- pair generation into bitmap: one wave per node, 256 pairs
__global__ __launch_bounds__(256) void pairs_bm(const int* __restrict__ dstA, const int* __restrict__ clu,
                                                unsigned* __restrict__ bm) {
    __shared__ int cb[4][16];
    int w = threadIdx.x >> 6, l = threadIdx.x & 63;
    int n = blockIdx.x * 4 + w;
    if (l < 16) {
        int d = dstA[n * 8 + (l >> 1)];
        cb[w][l] = clu[d * 2 + (l & 1)];
    }
    __syncthreads();
#pragma unroll
    for (int q = 0; q < 4; ++q) {
        int p = (l << 2) | q;
        unsigned enc = (unsigned)cb[w][p >> 4] * 25000u + (unsigned)cb[w][p & 15];
        atomicOr(&bm[enc >> 5], 1u << (enc & 31));
    }
}

// ---------------- bitmap popcount per scan-block (4096 words each)
__global__ __launch_bounds__(256) void bm_reduce(const unsigned* __restrict__ bm, int* __restrict__ bsum) {
    __shared__ int s[256];
    int t = threadIdx.x;
    size_t base = (size_t)blockIdx.x * BM_WPB;
    int acc = 0;
#pragma unroll
    for (int w = 0; w < 16; ++w) acc += __popc(bm[base + w * 256 + t]);
    s[t] = acc;
    __syncthreads();
    for (int o = 128; o > 0; o >>= 1) { if (t < o) s[t] += s[t + o]; __syncthreads(); }
    if (t == 0) bsum[blockIdx.x] = s[0];
}

// ---------------- emit sorted-unique enc values + edge_attr
__global__ __launch_bounds__(256) void emit(const unsigned* __restrict__ bm, const int* __restrict__ bscan,
                                            const float* __restrict__ newpos,
                                            float* __restrict__ ei0, float* __restrict__ ei1,
                                            float* __restrict__ attr) {
    __shared__ int s[256];
    int t  = threadIdx.x;
    size_t base = (size_t)blockIdx.x * BM_WPB;
    int rb = bscan[blockIdx.x];
    for (int w = 0; w < 16; ++w) {
        unsigned idx  = (unsigned)(base + w * 256 + t);
        unsigned word = bm[idx];
        int pc = __popc(word);
        s[t] = pc;
        __syncthreads();
        for (int o = 1; o < 256; o <<= 1) {
            int x = (t >= o) ? s[t - o] : 0;
            __syncthreads();
            s[t] += x;
            __syncthreads();
        }
        int rank = rb + s[t] - pc;
        int tot  = s[255];
        while (word) {
            int b = __ffs(word) - 1;
            word &= word - 1;
            unsigned v  = idx * 32u + (unsigned)b;
            unsigned ns = v / 25000u;
            unsigned nd = v - ns * 25000u;
            ei0[rank] = (float)ns;
            ei1[rank] = (float)nd;
            float dx = newpos[nd * 3 + 0] - newpos[ns * 3 + 0];
            float dy = newpos[nd * 3 + 1] - newpos[ns * 3 + 1];
            float dz = newpos[nd * 3 + 2] - newpos[ns * 3 + 2];
            attr[(size_t)3 * rank + 0] = dx;
            attr[(size_t)3 * rank + 1] = dy;
            attr[(size_t)3 * rank + 2] = dz;
            ++rank;
        }
        rb += tot;
        __syncthreads();
    }
}

// ---------------- zero the padded tail (slots >= U)
__global__ __launch_bounds__(256) void tail_zero(const int* __restrict__ Uptr,
                                                 float* __restrict__ ei0, float* __restrict__ ei1,
                                                 float* __restrict__ attr) {
    int i = blockIdx.x * 256 + threadIdx.x;
    if (i >= TOTE) return;
    if (i >= *Uptr) {
        ei0[i] = 0.f;
        ei1[i] = 0.f;
        attr[(size_t)3 * i + 0] = 0.f;
        attr[(size_t)3 * i + 1] = 0.f;
        attr[(size_t)3 * i + 2] = 0.f;
    }
}

extern "C" void kernel_launch(void* const* d_in, const int* in_sizes, int n_in,
                              void* d_out, int out_size, void* d_ws, size_t ws_size,
                              hipStream_t stream) {
    const float* x     = (const float*)d_in[0];
    const float* pos   = (const float*)d_in[1];
    const int*   dstA  = (const int*)d_in[2] + N_EDGES;   // edge_index row 1
    const float* ea    = (const float*)d_in[3];
    const int*   clu   = (const int*)d_in[5];
    const float* Wconv = (const float*)d_in[6];           // (128,144)
    const float* Wce   = (const float*)d_in[7];           // (3,144)
    const float* Wg    = (const float*)d_in[9];           // (128,128)

    // ---- output layout (floats): x_new | new_pos | ei0 | ei1 | attr
    float* out_f  = (float*)d_out;
    float* xnew   = out_f;                       // 3,200,000
    float* newpos = out_f + 3200000;             // 75,000
    float* ei0    = out_f + 3275000;             // 12,800,000
    float* ei1    = out_f + 16075000;            // 12,800,000
    float* attr   = out_f + 28875000;            // 38,400,000
    // scratch aliased into attr region (dead before emit/tail write attr)
    float* y      = attr;                        // 6,400,000 floats (N x 128)
    float* h      = attr + 6400000;              // 6,400,000 floats
    float* hW     = y;                           // reuse after y is consumed

    // ---- workspace layout
    uint8_t* w8 = (uint8_t*)d_ws;
    unsigned* bm   = (unsigned*)(w8);                         // 78,135,296 B
    int* cnt       = (int*)(w8 + 78135296);                   // 200,000
    int* offs      = (int*)(w8 + 78335296);                   // 200,000
    int* cursors   = (int*)(w8 + 78535296);                   // 200,000
    int* eids      = (int*)(w8 + 78735296);                   // 1,600,000
    int* cnt2      = (int*)(w8 + 80335296);                   // 100,000
    int* offs2     = (int*)(w8 + 80435296);                   // 100,000
    int* cursors2  = (int*)(w8 + 80535296);                   // 100,000
    int* bids      = (int*)(w8 + 80635296);                   // 400,000
    int* bsum      = (int*)(w8 + 81035296);                   // 20,480
    int* Uptr      = (int*)(w8 + 81055776);                   // 4

    // ---- zero-init
    hipMemsetAsync(bm,   0, (size_t)BM_WORDS_PAD * 4, stream);
    hipMemsetAsync(cnt,  0, N_NODES * 4, stream);
    hipMemsetAsync(cnt2, 0, C_CL * 4, stream);

    // ---- y = x @ W_conv[:, 16:144]   (only h-columns survive to outputs)
    mm128<<<(N_NODES * 32) / 256, 256, 0, stream>>>(x, 128, Wconv, 144, 16, y, N_NODES);

    // ---- CSR over dst
    hist_idx<<<(N_EDGES + 255) / 256, 256, 0, stream>>>(dstA, N_EDGES, cnt);
    reduce_blk<<<196, 256, 0, stream>>>(cnt, N_NODES, bsum);
    scan_small<<<1, 256, 0, stream>>>(bsum, 196, nullptr);
    scan_offs<<<196, 256, 0, stream>>>(cnt, N_NODES, bsum, offs);
    hipMemcpyAsync(cursors, offs, N_NODES * 4, hipMemcpyDeviceToDevice, stream);
    scatter_ids<<<(N_EDGES + 255) / 256, 256, 0, stream>>>(dstA, N_EDGES, cursors, eids);

    // ---- h = seg_mean(y[src] + ea@Wce[:,16:], dst)
    gather_h<<<N_NODES / 4, 256, 0, stream>>>(y, ea, offs, cnt, eids, Wce, h);

    // ---- hW = h @ W_gather  (into y's buffer)
    mm128<<<(N_NODES * 32) / 256, 256, 0, stream>>>(h, 128, Wg, 128, 0, hW, N_NODES);

    // ---- CSR over clusters (100k bloom entries, b>>1 = node)
    hist_idx<<<(NK + 255) / 256, 256, 0, stream>>>(clu, NK, cnt2);
    reduce_blk<<<98, 256, 0, stream>>>(cnt2, C_CL, bsum);
    scan_small<<<1, 256, 0, stream>>>(bsum, 98, nullptr);
    scan_offs<<<98, 256, 0, stream>>>(cnt2, C_CL, bsum, offs2);
    hipMemcpyAsync(cursors2, offs2, C_CL * 4, hipMemcpyDeviceToDevice, stream);
    scatter_ids<<<(NK + 255) / 256, 256, 0, stream>>>(clu, NK, cursors2, bids);

    // ---- x_new, new_pos (g_attr term sums to ~0 per cluster -> dropped)
    gather_out<<<C_CL / 4, 256, 0, stream>>>(hW, pos, offs2, cnt2, bids, xnew, newpos);

    // ---- pair bitmap + sorted-unique emission (replaces sort-based jnp.unique)
    pairs_bm<<<N_NODES / 4, 256, 0, stream>>>(dstA, clu, bm);
    bm_reduce<<<BM_NB, 256, 0, stream>>>(bm, bsum);
    scan_small<<<1, 256, 0, stream>>>(bsum, BM_NB, Uptr);
    emit<<<BM_NB, 256, 0, stream>>>(bm, bsum, newpos, ei0, ei1, attr);
    tail_zero<<<TOTE / 256, 256, 0, stream>>>(Uptr, ei0, ei1, attr);

    (void)in_sizes; (void)n_in; (void)out_size; (void)ws_size;
}

// Round 2
// 1365.882 us; speedup vs baseline: 1.0237x; 1.0237x over previous
//
#include <hip/hip_runtime.h>
#include <hip/hip_bf16.h>
#include <stdint.h>

#define N_NODES   50000
#define N_EDGES   400000
#define NK        100000
#define C_CL      25000
#define TOTE      12800000            // N * 16 * 16 pair slots
#define CHUNK_BITS 18                 // 2^18 enc values per chunk -> 32KB LDS bitmap
#define NCHUNK    2385                // ceil(625e6 / 2^18)
#define HIST_BLOCKS 782               // ceil(N / 64)

// ---------------- generic 128-K matmul: out[r][c] = sum_k A[r][k] * B[k][bcol0+c], c<128
__global__ __launch_bounds__(256) void mm128(const float* __restrict__ A, int lda,
                                             const float* __restrict__ B, int ldb, int bcol0,
                                             float* __restrict__ out, int rows) {
    int t = blockIdx.x * 256 + threadIdx.x;
    int r = t >> 5;
    int c = (t & 31) << 2;
    if (r >= rows) return;
    const float* Ar = A + (size_t)r * lda;
    const float* Bc = B + bcol0 + c;
    float4 acc = make_float4(0.f, 0.f, 0.f, 0.f);
#pragma unroll
    for (int k = 0; k < 128; k += 4) {
        float4 a  = *(const float4*)(Ar + k);
        float4 b0 = *(const float4*)(Bc + (size_t)(k + 0) * ldb);
        float4 b1 = *(const float4*)(Bc + (size_t)(k + 1) * ldb);
        float4 b2 = *(const float4*)(Bc + (size_t)(k + 2) * ldb);
        float4 b3 = *(const float4*)(Bc + (size_t)(k + 3) * ldb);
        acc.x += a.x * b0.x + a.y * b1.x + a.z * b2.x + a.w * b3.x;
        acc.y += a.x * b0.y + a.y * b1.y + a.z * b2.y + a.w * b3.y;
        acc.z += a.x * b0.z + a.y * b1.z + a.z * b2.z + a.w * b3.z;
        acc.w += a.x * b0.w + a.y * b1.w + a.z * b2.w + a.w * b3.w;
    }
    *(float4*)(out + (size_t)r * 128 + c) = acc;
}

// ---------------- histograms
__global__ __launch_bounds__(256) void hist_idx(const int* __restrict__ idx, int n, int* __restrict__ cnt) {
    int i = blockIdx.x * 256 + threadIdx.x;
    if (i < n) atomicAdd(&cnt[idx[i]], 1);
}

// ---------------- per-block sum (256 elems/block)
__global__ __launch_bounds__(256) void reduce_blk(const int* __restrict__ v, int n, int* __restrict__ bsum) {
    __shared__ int s[256];
    int t = threadIdx.x;
    int i = blockIdx.x * 256 + t;
    s[t] = (i < n) ? v[i] : 0;
    __syncthreads();
    for (int o = 128; o > 0; o >>= 1) { if (t < o) s[t] += s[t + o]; __syncthreads(); }
    if (t == 0) bsum[blockIdx.x] = s[0];
}

// ---------------- single-block exclusive scan (in place), optional grand total out
__global__ __launch_bounds__(256) void scan_small(int* data, int n, int* total_out) {
    __shared__ int s[256];
    __shared__ int carry;
    int t = threadIdx.x;
    if (t == 0) carry = 0;
    __syncthreads();
    for (int base = 0; base < n; base += 256) {
        int i = base + t;
        int v = (i < n) ? data[i] : 0;
        s[t] = v;
        __syncthreads();
        for (int o = 1; o < 256; o <<= 1) {
            int x = (t >= o) ? s[t - o] : 0;
            __syncthreads();
            s[t] += x;
            __syncthreads();
        }
        int inc = s[t];
        int tot = s[255];
        int cy  = carry;
        __syncthreads();
        if (i < n) data[i] = cy + inc - v;   // exclusive
        if (t == 0) carry = cy + tot;
        __syncthreads();
    }
    if (t == 0 && total_out) *total_out = carry;
}

// ---------------- final exclusive offsets: offs[i] = bscan[blk] + local exclusive prefix
__global__ __launch_bounds__(256) void scan_offs(const int* __restrict__ cnt, int n,
                                                 const int* __restrict__ bscan, int* __restrict__ offs) {
    __shared__ int s[256];
    int t = threadIdx.x;
    int i = blockIdx.x * 256 + t;
    int v = (i < n) ? cnt[i] : 0;
    s[t] = v;
    __syncthreads();
    for (int o = 1; o < 256; o <<= 1) {
        int x = (t >= o) ? s[t - o] : 0;
        __syncthreads();
        s[t] += x;
        __syncthreads();
    }
    if (i < n) offs[i] = bscan[blockIdx.x] + s[t] - v;
}

// ---------------- scatter indices into CSR lists
__global__ __launch_bounds__(256) void scatter_ids(const int* __restrict__ idx, int n,
                                                   int* __restrict__ cursors, int* __restrict__ ids) {
    int i = blockIdx.x * 256 + threadIdx.x;
    if (i < n) {
        int p = atomicAdd(&cursors[idx[i]], 1);
        ids[p] = i;
    }
}

// ---------------- per-dst-node gather: h[n] = (sum y[src] + (sum ea) @ Wce[:,16:]) / max(cnt,1)
__global__ __launch_bounds__(256) void gather_h(const float* __restrict__ y, const float* __restrict__ ea,
                                                const int* __restrict__ offs, const int* __restrict__ cnt,
                                                const int* __restrict__ eids, const float* __restrict__ Wce,
                                                float* __restrict__ h) {
    int l = threadIdx.x & 63;
    int n = blockIdx.x * 4 + (threadIdx.x >> 6);
    int off = offs[n], m = cnt[n];
    float ax = 0.f, ay = 0.f, ae = 0.f;
    for (int i = 0; i < m; ++i) {
        int e = eids[off + i];
        int s = e >> 3;                                   // src = e / DEG
        float2 v = *(const float2*)(y + (size_t)s * 128 + 2 * l);
        ax += v.x; ay += v.y;
        if (l < 3) ae += ea[(size_t)e * 3 + l];
    }
    float e0 = __shfl(ae, 0), e1 = __shfl(ae, 1), e2 = __shfl(ae, 2);
    float inv = 1.f / (float)(m > 0 ? m : 1);
    int c0 = 2 * l, c1 = 2 * l + 1;
    float h0 = (ax + e0 * Wce[16 + c0] + e1 * Wce[144 + 16 + c0] + e2 * Wce[288 + 16 + c0]) * inv;
    float h1 = (ay + e0 * Wce[16 + c1] + e1 * Wce[144 + 16 + c1] + e2 * Wce[288 + 16 + c1]) * inv;
    *(float2*)(h + (size_t)n * 128 + 2 * l) = make_float2(h0, h1);
}

// ---------------- per-cluster gather: x_new[c] = sum hW[b>>1]/max(cnt,1); new_pos[c] = sum pos[b>>1]/max(cnt,1)
__global__ __launch_bounds__(256) void gather_out(const float* __restrict__ hW, const float* __restrict__ pos,
                                                  const int* __restrict__ offs2, const int* __restrict__ cnt2,
                                                  const int* __restrict__ bids,
                                                  float* __restrict__ xnew, float* __restrict__ newpos) {
    int l = threadIdx.x & 63;
    int c = blockIdx.x * 4 + (threadIdx.x >> 6);
    int off = offs2[c], m = cnt2[c];
    float ax = 0.f, ay = 0.f, ap = 0.f;
    for (int i = 0; i < m; ++i) {
        int b  = bids[off + i];
        int nd = b >> 1;
        float2 v = *(const float2*)(hW + (size_t)nd * 128 + 2 * l);
        ax += v.x; ay += v.y;
        if (l < 3) ap += pos[(size_t)nd * 3 + l];
    }
    float inv = 1.f / (float)(m > 0 ? m : 1);
    *(float2*)(xnew + (size_t)c * 128 + 2 * l) = make_float2(ax * inv, ay * inv);
    if (l < 3) newpos[(size_t)c * 3 + l] = ap * inv;
}

// ---------------- pass 1: per-WG LDS histogram of pair chunks (64 nodes/WG)
__global__ __launch_bounds__(256) void pair_hist(const int* __restrict__ dstA, const int* __restrict__ clu,
                                                 int* __restrict__ gcnt) {
    __shared__ int cb[64][16];
    __shared__ int hist[NCHUNK];
    int t = threadIdx.x;
    int n0 = blockIdx.x * 64;
    int nvalid = N_NODES - n0; if (nvalid > 64) nvalid = 64;
    for (int i = t; i < NCHUNK; i += 256) hist[i] = 0;
    for (int i = t; i < 1024; i += 256) {
        int ln = i >> 4, j = i & 15;
        if (ln < nvalid) {
            int d = dstA[(n0 + ln) * 8 + (j >> 1)];
            cb[ln][j] = clu[d * 2 + (j & 1)];
        }
    }
    __syncthreads();
#pragma unroll 4
    for (int q = 0; q < 64; ++q) {
        int idx = t * 64 + q;
        int ln = idx >> 8, p = idx & 255;
        if (ln < nvalid) {
            unsigned enc = (unsigned)cb[ln][p >> 4] * 25000u + (unsigned)cb[ln][p & 15];
            atomicAdd(&hist[enc >> CHUNK_BITS], 1);
        }
    }
    __syncthreads();
    for (int i = t; i < NCHUNK; i += 256) { int h = hist[i]; if (h) atomicAdd(&gcnt[i], h); }
}

// ---------------- pass 2: two-level scatter of enc values into chunk-ordered buffer
__global__ __launch_bounds__(256) void pair_scatter(const int* __restrict__ dstA, const int* __restrict__ clu,
                                                    int* __restrict__ gcur, unsigned* __restrict__ pbuf) {
    __shared__ int cb[64][16];
    __shared__ int hist[NCHUNK];
    __shared__ int lcur[NCHUNK];
    int t = threadIdx.x;
    int n0 = blockIdx.x * 64;
    int nvalid = N_NODES - n0; if (nvalid > 64) nvalid = 64;
    for (int i = t; i < NCHUNK; i += 256) hist[i] = 0;
    for (int i = t; i < 1024; i += 256) {
        int ln = i >> 4, j = i & 15;
        if (ln < nvalid) {
            int d = dstA[(n0 + ln) * 8 + (j >> 1)];
            cb[ln][j] = clu[d * 2 + (j & 1)];
        }
    }
    __syncthreads();
#pragma unroll 4
    for (int q = 0; q < 64; ++q) {
        int idx = t * 64 + q;
        int ln = idx >> 8, p = idx & 255;
        if (ln < nvalid) {
            unsigned enc = (unsigned)cb[ln][p >> 4] * 25000u + (unsigned)cb[ln][p & 15];
            atomicAdd(&hist[enc >> CHUNK_BITS], 1);
        }
    }
    __syncthreads();
    for (int i = t; i < NCHUNK; i += 256) { int h = hist[i]; if (h) lcur[i] = atomicAdd(&gcur[i], h); }
    __syncthreads();
#pragma unroll 4
    for (int q = 0; q < 64; ++q) {
        int idx = t * 64 + q;
        int ln = idx >> 8, p = idx & 255;
        if (ln < nvalid) {
            unsigned enc = (unsigned)cb[ln][p >> 4] * 25000u + (unsigned)cb[ln][p & 15];
            int pos = atomicAdd(&lcur[enc >> CHUNK_BITS], 1);
            pbuf[pos] = enc;
        }
    }
}

// ---------------- pass 3: per-chunk LDS bitmap -> unique count
__global__ __launch_bounds__(256) void chunk_count(const unsigned* __restrict__ pbuf,
                                                   const int* __restrict__ goffs, const int* __restrict__ gcnt,
                                                   int* __restrict__ ucnt) {
    __shared__ unsigned bm[8192];
    __shared__ int s[256];
    int t = threadIdx.x, c = blockIdx.x;
    for (int i = t; i < 8192; i += 256) bm[i] = 0;
    __syncthreads();
    int off = goffs[c], m = gcnt[c];
    unsigned basee = (unsigned)c << CHUNK_BITS;
    for (int i = t; i < m; i += 256) {
        unsigned e = pbuf[off + i] - basee;
        atomicOr(&bm[e >> 5], 1u << (e & 31));
    }
    __syncthreads();
    int acc = 0;
#pragma unroll
    for (int w = 0; w < 32; ++w) acc += __popc(bm[t * 32 + w]);
    s[t] = acc;
    __syncthreads();
    for (int o = 128; o > 0; o >>= 1) { if (t < o) s[t] += s[t + o]; __syncthreads(); }
    if (t == 0) ucnt[c] = s[0];
}

// ---------------- pass 4: rebuild LDS bitmap, emit sorted-unique enc + edge_attr
__global__ __launch_bounds__(256) void chunk_emit(const unsigned* __restrict__ pbuf,
                                                  const int* __restrict__ goffs, const int* __restrict__ gcnt,
                                                  const int* __restrict__ uoffs, const float* __restrict__ newpos,
                                                  float* __restrict__ ei0, float* __restrict__ ei1,
                                                  float* __restrict__ attr) {
    __shared__ unsigned bm[8192];
    __shared__ int s[256];
    int t = threadIdx.x, c = blockIdx.x;
    for (int i = t; i < 8192; i += 256) bm[i] = 0;
    __syncthreads();
    int off = goffs[c], m = gcnt[c];
    unsigned basee = (unsigned)c << CHUNK_BITS;
    for (int i = t; i < m; i += 256) {
        unsigned e = pbuf[off + i] - basee;
        atomicOr(&bm[e >> 5], 1u << (e & 31));
    }
    __syncthreads();
    int acc = 0;
#pragma unroll
    for (int w = 0; w < 32; ++w) acc += __popc(bm[t * 32 + w]);
    s[t] = acc;
    __syncthreads();
    for (int o = 1; o < 256; o <<= 1) {
        int x = (t >= o) ? s[t - o] : 0;
        __syncthreads();
        s[t] += x;
        __syncthreads();
    }
    int rank = uoffs[c] + s[t] - acc;      // exclusive prefix for this thread's 32 words
    for (int w = 0; w < 32; ++w) {
        unsigned word = bm[t * 32 + w];
        unsigned wbase = basee + (((unsigned)(t * 32 + w)) << 5);
        while (word) {
            int b = __ffs(word) - 1;
            word &= word - 1;
            unsigned v  = wbase + (unsigned)b;
            unsigned ns = v / 25000u;
            unsigned nd = v - ns * 25000u;
            ei0[rank] = (float)ns;
            ei1[rank] = (float)nd;
            float dx = newpos[nd * 3 + 0] - newpos[ns * 3 + 0];
            float dy = newpos[nd * 3 + 1] - newpos[ns * 3 + 1];
            float dz = newpos[nd * 3 + 2] - newpos[ns * 3 + 2];
            attr[(size_t)3 * rank + 0] = dx;
            attr[(size_t)3 * rank + 1] = dy;
            attr[(size_t)3 * rank + 2] = dz;
            ++rank;
        }
    }
}

// ---------------- zero the padded tail (slots >= U)
__global__ __launch_bounds__(256) void tail_zero(const int* __restrict__ Uptr,
                                                 float* __restrict__ ei0, float* __restrict__ ei1,
                                                 float* __restrict__ attr) {
    int i = blockIdx.x * 256 + threadIdx.x;
    if (i >= TOTE) return;
    if (i >= *Uptr) {
        ei0[i] = 0.f;
        ei1[i] = 0.f;
        attr[(size_t)3 * i + 0] = 0.f;
        attr[(size_t)3 * i + 1] = 0.f;
        attr[(size_t)3 * i + 2] = 0.f;
    }
}

extern "C" void kernel_launch(void* const* d_in, const int* in_sizes, int n_in,
                              void* d_out, int out_size, void* d_ws, size_t ws_size,
                              hipStream_t stream) {
    const float* x     = (const float*)d_in[0];
    const float* pos   = (const float*)d_in[1];
    const int*   dstA  = (const int*)d_in[2] + N_EDGES;   // edge_index row 1
    const float* ea    = (const float*)d_in[3];
    const int*   clu   = (const int*)d_in[5];
    const float* Wconv = (const float*)d_in[6];           // (128,144)
    const float* Wce   = (const float*)d_in[7];           // (3,144)
    const float* Wg    = (const float*)d_in[9];           // (128,128)

    // ---- output layout (floats): x_new | new_pos | ei0 | ei1 | attr
    float* out_f  = (float*)d_out;
    float* xnew   = out_f;                       // 3,200,000
    float* newpos = out_f + 3200000;             // 75,000
    float* ei0    = out_f + 3275000;             // 12,800,000
    float* ei1    = out_f + 16075000;            // 12,800,000
    float* attr   = out_f + 28875000;            // 38,400,000
    // scratch aliased into attr region (dead before chunk_emit/tail write attr)
    float* y      = attr;                        // 6,400,000 floats (N x 128)
    float* h      = attr + 6400000;              // 6,400,000 floats
    float* hW     = y;                           // reuse after y is consumed

    // ---- workspace layout
    uint8_t* w8 = (uint8_t*)d_ws;
    unsigned* pbuf = (unsigned*)(w8);                         // 51,200,000 B
    int* cnt       = (int*)(w8 + 51200000);                   // 200,000
    int* offs      = (int*)(w8 + 51400000);                   // 200,000
    int* cursors   = (int*)(w8 + 51600000);                   // 200,000
    int* eids      = (int*)(w8 + 51800000);                   // 1,600,000
    int* cnt2      = (int*)(w8 + 53400000);                   // 100,000
    int* offs2     = (int*)(w8 + 53500000);                   // 100,000
    int* cursors2  = (int*)(w8 + 53600000);                   // 100,000
    int* bids      = (int*)(w8 + 53700000);                   // 400,000
    int* bsum      = (int*)(w8 + 54100000);                   // 20,480
    int* gcnt      = (int*)(w8 + 54120480);                   // 9,540
    int* goffs     = (int*)(w8 + 54130020);                   // 9,540
    int* gcur      = (int*)(w8 + 54139560);                   // 9,540
    int* ucnt      = (int*)(w8 + 54149100);                   // 9,540
    int* uoffs     = (int*)(w8 + 54158640);                   // 9,540
    int* Uptr      = (int*)(w8 + 54168180);                   // 4

    // ---- zero-init
    hipMemsetAsync(gcnt, 0, NCHUNK * 4, stream);
    hipMemsetAsync(cnt,  0, N_NODES * 4, stream);
    hipMemsetAsync(cnt2, 0, C_CL * 4, stream);

    // ---- y = x @ W_conv[:, 16:144]   (only h-columns survive to outputs)
    mm128<<<(N_NODES * 32) / 256, 256, 0, stream>>>(x, 128, Wconv, 144, 16, y, N_NODES);

    // ---- CSR over dst
    hist_idx<<<(N_EDGES + 255) / 256, 256, 0, stream>>>(dstA, N_EDGES, cnt);
    reduce_blk<<<196, 256, 0, stream>>>(cnt, N_NODES, bsum);
    scan_small<<<1, 256, 0, stream>>>(bsum, 196, nullptr);
    scan_offs<<<196, 256, 0, stream>>>(cnt, N_NODES, bsum, offs);
    hipMemcpyAsync(cursors, offs, N_NODES * 4, hipMemcpyDeviceToDevice, stream);
    scatter_ids<<<(N_EDGES + 255) / 256, 256, 0, stream>>>(dstA, N_EDGES, cursors, eids);

    // ---- h = seg_mean(y[src] + ea@Wce[:,16:], dst)
    gather_h<<<N_NODES / 4, 256, 0, stream>>>(y, ea, offs, cnt, eids, Wce, h);

    // ---- hW = h @ W_gather  (into y's buffer)
    mm128<<<(N_NODES * 32) / 256, 256, 0, stream>>>(h, 128, Wg, 128, 0, hW, N_NODES);

    // ---- CSR over clusters (100k bloom entries, b>>1 = node)
    hist_idx<<<(NK + 255) / 256, 256, 0, stream>>>(clu, NK, cnt2);
    reduce_blk<<<98, 256, 0, stream>>>(cnt2, C_CL, bsum);
    scan_small<<<1, 256, 0, stream>>>(bsum, 98, nullptr);
    scan_offs<<<98, 256, 0, stream>>>(cnt2, C_CL, bsum, offs2);
    hipMemcpyAsync(cursors2, offs2, C_CL * 4, hipMemcpyDeviceToDevice, stream);
    scatter_ids<<<(NK + 255) / 256, 256, 0, stream>>>(clu, NK, cursors2, bids);

    // ---- x_new, new_pos (g_attr term sums to ~0 per cluster -> dropped)
    gather_out<<<C_CL / 4, 256, 0, stream>>>(hW, pos, offs2, cnt2, bids, xnew, newpos);

    // ---- pair pipeline: bin by enc>>18, per-chunk LDS bitmap, sorted-unique emission
    pair_hist<<<HIST_BLOCKS, 256, 0, stream>>>(dstA, clu, gcnt);
    hipMemcpyAsync(goffs, gcnt, NCHUNK * 4, hipMemcpyDeviceToDevice, stream);
    scan_small<<<1, 256, 0, stream>>>(goffs, NCHUNK, nullptr);
    hipMemcpyAsync(gcur, goffs, NCHUNK * 4, hipMemcpyDeviceToDevice, stream);
    pair_scatter<<<HIST_BLOCKS, 256, 0, stream>>>(dstA, clu, gcur, pbuf);
    chunk_count<<<NCHUNK, 256, 0, stream>>>(pbuf, goffs, gcnt, ucnt);
    hipMemcpyAsync(uoffs, ucnt, NCHUNK * 4, hipMemcpyDeviceToDevice, stream);
    scan_small<<<1, 256, 0, stream>>>(uoffs, NCHUNK, Uptr);
    chunk_emit<<<NCHUNK, 256, 0, stream>>>(pbuf, goffs, gcnt, uoffs, newpos, ei0, ei1, attr);
    tail_zero<<<TOTE / 256, 256, 0, stream>>>(Uptr, ei0, ei1, attr);

    (void)in_sizes; (void)n_in; (void)out_size; (void)ws_size;
}

// Round 3
// 1126.984 us; speedup vs baseline: 1.2407x; 1.2120x over previous
//
#include <hip/hip_runtime.h>
#include <hip/hip_bf16.h>
#include <stdint.h>

#define N_NODES   50000
#define N_EDGES   400000
#define NK        100000
#define C_CL      25000
#define TOTE      12800000            // N * 16 * 16 pair slots
#define CHUNK_BITS 18                 // 2^18 enc values per chunk -> 32KB LDS bitmap
#define NCHUNK    2385                // ceil(625e6 / 2^18)
#define HIST_BLOCKS 782               // ceil(N / 64)

// ---------------- generic 128-K matmul: out[r][c] = sum_k A[r][k] * B[k][bcol0+c], c<128
__global__ __launch_bounds__(256) void mm128(const float* __restrict__ A, int lda,
                                             const float* __restrict__ B, int ldb, int bcol0,
                                             float* __restrict__ out, int rows) {
    int t = blockIdx.x * 256 + threadIdx.x;
    int r = t >> 5;
    int c = (t & 31) << 2;
    if (r >= rows) return;
    const float* Ar = A + (size_t)r * lda;
    const float* Bc = B + bcol0 + c;
    float4 acc = make_float4(0.f, 0.f, 0.f, 0.f);
#pragma unroll
    for (int k = 0; k < 128; k += 4) {
        float4 a  = *(const float4*)(Ar + k);
        float4 b0 = *(const float4*)(Bc + (size_t)(k + 0) * ldb);
        float4 b1 = *(const float4*)(Bc + (size_t)(k + 1) * ldb);
        float4 b2 = *(const float4*)(Bc + (size_t)(k + 2) * ldb);
        float4 b3 = *(const float4*)(Bc + (size_t)(k + 3) * ldb);
        acc.x += a.x * b0.x + a.y * b1.x + a.z * b2.x + a.w * b3.x;
        acc.y += a.x * b0.y + a.y * b1.y + a.z * b2.y + a.w * b3.y;
        acc.z += a.x * b0.z + a.y * b1.z + a.z * b2.z + a.w * b3.z;
        acc.w += a.x * b0.w + a.y * b1.w + a.z * b2.w + a.w * b3.w;
    }
    *(float4*)(out + (size_t)r * 128 + c) = acc;
}

// ---------------- histograms
__global__ __launch_bounds__(256) void hist_idx(const int* __restrict__ idx, int n, int* __restrict__ cnt) {
    int i = blockIdx.x * 256 + threadIdx.x;
    if (i < n) atomicAdd(&cnt[idx[i]], 1);
}

// ---------------- per-block sum (256 elems/block)
__global__ __launch_bounds__(256) void reduce_blk(const int* __restrict__ v, int n, int* __restrict__ bsum) {
    __shared__ int s[256];
    int t = threadIdx.x;
    int i = blockIdx.x * 256 + t;
    s[t] = (i < n) ? v[i] : 0;
    __syncthreads();
    for (int o = 128; o > 0; o >>= 1) { if (t < o) s[t] += s[t + o]; __syncthreads(); }
    if (t == 0) bsum[blockIdx.x] = s[0];
}

// ---------------- single-block exclusive scan (in place), optional grand total out
__global__ __launch_bounds__(256) void scan_small(int* data, int n, int* total_out) {
    __shared__ int s[256];
    __shared__ int carry;
    int t = threadIdx.x;
    if (t == 0) carry = 0;
    __syncthreads();
    for (int base = 0; base < n; base += 256) {
        int i = base + t;
        int v = (i < n) ? data[i] : 0;
        s[t] = v;
        __syncthreads();
        for (int o = 1; o < 256; o <<= 1) {
            int x = (t >= o) ? s[t - o] : 0;
            __syncthreads();
            s[t] += x;
            __syncthreads();
        }
        int inc = s[t];
        int tot = s[255];
        int cy  = carry;
        __syncthreads();
        if (i < n) data[i] = cy + inc - v;   // exclusive
        if (t == 0) carry = cy + tot;
        __syncthreads();
    }
    if (t == 0 && total_out) *total_out = carry;
}

// ---------------- final exclusive offsets: offs[i] = bscan[blk] + local exclusive prefix
__global__ __launch_bounds__(256) void scan_offs(const int* __restrict__ cnt, int n,
                                                 const int* __restrict__ bscan, int* __restrict__ offs) {
    __shared__ int s[256];
    int t = threadIdx.x;
    int i = blockIdx.x * 256 + t;
    int v = (i < n) ? cnt[i] : 0;
    s[t] = v;
    __syncthreads();
    for (int o = 1; o < 256; o <<= 1) {
        int x = (t >= o) ? s[t - o] : 0;
        __syncthreads();
        s[t] += x;
        __syncthreads();
    }
    if (i < n) offs[i] = bscan[blockIdx.x] + s[t] - v;
}

// ---------------- scatter indices into CSR lists
__global__ __launch_bounds__(256) void scatter_ids(const int* __restrict__ idx, int n,
                                                   int* __restrict__ cursors, int* __restrict__ ids) {
    int i = blockIdx.x * 256 + threadIdx.x;
    if (i < n) {
        int p = atomicAdd(&cursors[idx[i]], 1);
        ids[p] = i;
    }
}

// ---------------- per-dst-node gather: h[n] = (sum y[src] + (sum ea) @ Wce[:,16:]) / max(cnt,1)
__global__ __launch_bounds__(256) void gather_h(const float* __restrict__ y, const float* __restrict__ ea,
                                                const int* __restrict__ offs, const int* __restrict__ cnt,
                                                const int* __restrict__ eids, const float* __restrict__ Wce,
                                                float* __restrict__ h) {
    int l = threadIdx.x & 63;
    int n = blockIdx.x * 4 + (threadIdx.x >> 6);
    int off = offs[n], m = cnt[n];
    float ax = 0.f, ay = 0.f, ae = 0.f;
    for (int i = 0; i < m; ++i) {
        int e = eids[off + i];
        int s = e >> 3;                                   // src = e / DEG
        float2 v = *(const float2*)(y + (size_t)s * 128 + 2 * l);
        ax += v.x; ay += v.y;
        if (l < 3) ae += ea[(size_t)e * 3 + l];
    }
    float e0 = __shfl(ae, 0), e1 = __shfl(ae, 1), e2 = __shfl(ae, 2);
    float inv = 1.f / (float)(m > 0 ? m : 1);
    int c0 = 2 * l, c1 = 2 * l + 1;
    float h0 = (ax + e0 * Wce[16 + c0] + e1 * Wce[144 + 16 + c0] + e2 * Wce[288 + 16 + c0]) * inv;
    float h1 = (ay + e0 * Wce[16 + c1] + e1 * Wce[144 + 16 + c1] + e2 * Wce[288 + 16 + c1]) * inv;
    *(float2*)(h + (size_t)n * 128 + 2 * l) = make_float2(h0, h1);
}

// ---------------- per-cluster gather: x_new[c] = sum hW[b>>1]/max(cnt,1); new_pos[c] = sum pos[b>>1]/max(cnt,1)
__global__ __launch_bounds__(256) void gather_out(const float* __restrict__ hW, const float* __restrict__ pos,
                                                  const int* __restrict__ offs2, const int* __restrict__ cnt2,
                                                  const int* __restrict__ bids,
                                                  float* __restrict__ xnew, float* __restrict__ newpos) {
    int l = threadIdx.x & 63;
    int c = blockIdx.x * 4 + (threadIdx.x >> 6);
    int off = offs2[c], m = cnt2[c];
    float ax = 0.f, ay = 0.f, ap = 0.f;
    for (int i = 0; i < m; ++i) {
        int b  = bids[off + i];
        int nd = b >> 1;
        float2 v = *(const float2*)(hW + (size_t)nd * 128 + 2 * l);
        ax += v.x; ay += v.y;
        if (l < 3) ap += pos[(size_t)nd * 3 + l];
    }
    float inv = 1.f / (float)(m > 0 ? m : 1);
    *(float2*)(xnew + (size_t)c * 128 + 2 * l) = make_float2(ax * inv, ay * inv);
    if (l < 3) newpos[(size_t)c * 3 + l] = ap * inv;
}

// ---------------- pass 1: per-WG LDS histogram of pair chunks (64 nodes/WG)
__global__ __launch_bounds__(256) void pair_hist(const int* __restrict__ dstA, const int* __restrict__ clu,
                                                 int* __restrict__ gcnt) {
    __shared__ int cb[64][16];
    __shared__ int hist[NCHUNK];
    int t = threadIdx.x;
    int n0 = blockIdx.x * 64;
    int nvalid = N_NODES - n0; if (nvalid > 64) nvalid = 64;
    for (int i = t; i < NCHUNK; i += 256) hist[i] = 0;
    for (int i = t; i < 1024; i += 256) {
        int ln = i >> 4, j = i & 15;
        if (ln < nvalid) {
            int d = dstA[(n0 + ln) * 8 + (j >> 1)];
            cb[ln][j] = clu[d * 2 + (j & 1)];
        }
    }
    __syncthreads();
#pragma unroll 4
    for (int q = 0; q < 64; ++q) {
        int idx = t * 64 + q;
        int ln = idx >> 8, p = idx & 255;
        if (ln < nvalid) {
            unsigned enc = (unsigned)cb[ln][p >> 4] * 25000u + (unsigned)cb[ln][p & 15];
            atomicAdd(&hist[enc >> CHUNK_BITS], 1);
        }
    }
    __syncthreads();
    for (int i = t; i < NCHUNK; i += 256) { int h = hist[i]; if (h) atomicAdd(&gcnt[i], h); }
}

// ---------------- pass 2: two-level scatter of enc values into chunk-ordered buffer
__global__ __launch_bounds__(256) void pair_scatter(const int* __restrict__ dstA, const int* __restrict__ clu,
                                                    int* __restrict__ gcur, unsigned* __restrict__ pbuf) {
    __shared__ int cb[64][16];
    __shared__ int hist[NCHUNK];
    __shared__ int lcur[NCHUNK];
    int t = threadIdx.x;
    int n0 = blockIdx.x * 64;
    int nvalid = N_NODES - n0; if (nvalid > 64) nvalid = 64;
    for (int i = t; i < NCHUNK; i += 256) hist[i] = 0;
    for (int i = t; i < 1024; i += 256) {
        int ln = i >> 4, j = i & 15;
        if (ln < nvalid) {
            int d = dstA[(n0 + ln) * 8 + (j >> 1)];
            cb[ln][j] = clu[d * 2 + (j & 1)];
        }
    }
    __syncthreads();
#pragma unroll 4
    for (int q = 0; q < 64; ++q) {
        int idx = t * 64 + q;
        int ln = idx >> 8, p = idx & 255;
        if (ln < nvalid) {
            unsigned enc = (unsigned)cb[ln][p >> 4] * 25000u + (unsigned)cb[ln][p & 15];
            atomicAdd(&hist[enc >> CHUNK_BITS], 1);
        }
    }
    __syncthreads();
    for (int i = t; i < NCHUNK; i += 256) { int h = hist[i]; if (h) lcur[i] = atomicAdd(&gcur[i], h); }
    __syncthreads();
#pragma unroll 4
    for (int q = 0; q < 64; ++q) {
        int idx = t * 64 + q;
        int ln = idx >> 8, p = idx & 255;
        if (ln < nvalid) {
            unsigned enc = (unsigned)cb[ln][p >> 4] * 25000u + (unsigned)cb[ln][p & 15];
            int pos = atomicAdd(&lcur[enc >> CHUNK_BITS], 1);
            pbuf[pos] = enc;
        }
    }
}

// ---------------- pass 3: per-chunk LDS bitmap -> unique count (conflict-free popcount)
__global__ __launch_bounds__(256) void chunk_count(const unsigned* __restrict__ pbuf,
                                                   const int* __restrict__ goffs, const int* __restrict__ gcnt,
                                                   int* __restrict__ ucnt) {
    __shared__ unsigned bm[8192];
    __shared__ int s[256];
    int t = threadIdx.x, c = blockIdx.x;
    for (int i = t; i < 8192; i += 256) bm[i] = 0;
    __syncthreads();
    int off = goffs[c], m = gcnt[c];
    unsigned basee = (unsigned)c << CHUNK_BITS;
    for (int i = t; i < m; i += 256) {
        unsigned e = pbuf[off + i] - basee;
        atomicOr(&bm[e >> 5], 1u << (e & 31));
    }
    __syncthreads();
    int acc = 0;
#pragma unroll
    for (int w = 0; w < 32; ++w) acc += __popc(bm[w * 256 + t]);   // bank = t%32, conflict-free
    s[t] = acc;
    __syncthreads();
    for (int o = 128; o > 0; o >>= 1) { if (t < o) s[t] += s[t + o]; __syncthreads(); }
    if (t == 0) ucnt[c] = s[0];
}

// ---------------- pass 4: rebuild LDS bitmap, emit sorted-unique enc + edge_attr
// Interleaved word ownership: iteration g covers words [g*256, g*256+256) -> all 256
// threads emit into one dense rank window simultaneously (L2 merges sectors), and
// bm reads hit bank t%32 (conflict-free). Rank via wave shuffle-scan + 4-wave combine.
__global__ __launch_bounds__(256) void chunk_emit(const unsigned* __restrict__ pbuf,
                                                  const int* __restrict__ goffs, const int* __restrict__ gcnt,
                                                  const int* __restrict__ uoffs, const float* __restrict__ newpos,
                                                  float* __restrict__ ei0, float* __restrict__ ei1,
                                                  float* __restrict__ attr) {
    __shared__ unsigned bm[8192];
    __shared__ int wsum[32][4];
    int t = threadIdx.x, c = blockIdx.x;
    int lane = t & 63, wid = t >> 6;
    for (int i = t; i < 8192; i += 256) bm[i] = 0;
    __syncthreads();
    int off = goffs[c], m = gcnt[c];
    unsigned basee = (unsigned)c << CHUNK_BITS;
    for (int i = t; i < m; i += 256) {
        unsigned e = pbuf[off + i] - basee;
        atomicOr(&bm[e >> 5], 1u << (e & 31));
    }
    __syncthreads();
    int ubase = uoffs[c];
    int carry = 0;
    for (int g = 0; g < 32; ++g) {
        unsigned word = bm[g * 256 + t];
        int pc = __popc(word);
        int incl = pc;
#pragma unroll
        for (int o = 1; o < 64; o <<= 1) {
            int v = __shfl_up(incl, o, 64);
            if (lane >= o) incl += v;
        }
        if (lane == 63) wsum[g][wid] = incl;
        __syncthreads();
        int w0 = wsum[g][0], w1 = wsum[g][1], w2 = wsum[g][2], w3 = wsum[g][3];
        int wpre = (wid > 0 ? w0 : 0) + (wid > 1 ? w1 : 0) + (wid > 2 ? w2 : 0);
        int rank = ubase + carry + wpre + incl - pc;
        carry += w0 + w1 + w2 + w3;
        unsigned wbase = basee + (((unsigned)(g * 256 + t)) << 5);
        while (word) {
            int b = __ffs(word) - 1;
            word &= word - 1;
            unsigned v  = wbase + (unsigned)b;
            unsigned ns = v / 25000u;
            unsigned nd = v - ns * 25000u;
            ei0[rank] = (float)ns;
            ei1[rank] = (float)nd;
            float dx = newpos[nd * 3 + 0] - newpos[ns * 3 + 0];
            float dy = newpos[nd * 3 + 1] - newpos[ns * 3 + 1];
            float dz = newpos[nd * 3 + 2] - newpos[ns * 3 + 2];
            attr[(size_t)3 * rank + 0] = dx;
            attr[(size_t)3 * rank + 1] = dy;
            attr[(size_t)3 * rank + 2] = dz;
            ++rank;
        }
    }
}

// ---------------- zero the padded tail (slots >= U)
__global__ __launch_bounds__(256) void tail_zero(const int* __restrict__ Uptr,
                                                 float* __restrict__ ei0, float* __restrict__ ei1,
                                                 float* __restrict__ attr) {
    int i = blockIdx.x * 256 + threadIdx.x;
    if (i >= TOTE) return;
    if (i >= *Uptr) {
        ei0[i] = 0.f;
        ei1[i] = 0.f;
        attr[(size_t)3 * i + 0] = 0.f;
        attr[(size_t)3 * i + 1] = 0.f;
        attr[(size_t)3 * i + 2] = 0.f;
    }
}

extern "C" void kernel_launch(void* const* d_in, const int* in_sizes, int n_in,
                              void* d_out, int out_size, void* d_ws, size_t ws_size,
                              hipStream_t stream) {
    const float* x     = (const float*)d_in[0];
    const float* pos   = (const float*)d_in[1];
    const int*   dstA  = (const int*)d_in[2] + N_EDGES;   // edge_index row 1
    const float* ea    = (const float*)d_in[3];
    const int*   clu   = (const int*)d_in[5];
    const float* Wconv = (const float*)d_in[6];           // (128,144)
    const float* Wce   = (const float*)d_in[7];           // (3,144)
    const float* Wg    = (const float*)d_in[9];           // (128,128)

    // ---- output layout (floats): x_new | new_pos | ei0 | ei1 | attr
    float* out_f  = (float*)d_out;
    float* xnew   = out_f;                       // 3,200,000
    float* newpos = out_f + 3200000;             // 75,000
    float* ei0    = out_f + 3275000;             // 12,800,000
    float* ei1    = out_f + 16075000;            // 12,800,000
    float* attr   = out_f + 28875000;            // 38,400,000
    // scratch aliased into attr region (dead before chunk_emit/tail write attr)
    float* y      = attr;                        // 6,400,000 floats (N x 128)
    float* h      = attr + 6400000;              // 6,400,000 floats
    float* hW     = y;                           // reuse after y is consumed

    // ---- workspace layout
    uint8_t* w8 = (uint8_t*)d_ws;
    unsigned* pbuf = (unsigned*)(w8);                         // 51,200,000 B
    int* cnt       = (int*)(w8 + 51200000);                   // 200,000
    int* offs      = (int*)(w8 + 51400000);                   // 200,000
    int* cursors   = (int*)(w8 + 51600000);                   // 200,000
    int* eids      = (int*)(w8 + 51800000);                   // 1,600,000
    int* cnt2      = (int*)(w8 + 53400000);                   // 100,000
    int* offs2     = (int*)(w8 + 53500000);                   // 100,000
    int* cursors2  = (int*)(w8 + 53600000);                   // 100,000
    int* bids      = (int*)(w8 + 53700000);                   // 400,000
    int* bsum      = (int*)(w8 + 54100000);                   // 20,480
    int* gcnt      = (int*)(w8 + 54120480);                   // 9,540
    int* goffs     = (int*)(w8 + 54130020);                   // 9,540
    int* gcur      = (int*)(w8 + 54139560);                   // 9,540
    int* ucnt      = (int*)(w8 + 54149100);                   // 9,540
    int* uoffs     = (int*)(w8 + 54158640);                   // 9,540
    int* Uptr      = (int*)(w8 + 54168180);                   // 4

    // ---- zero-init
    hipMemsetAsync(gcnt, 0, NCHUNK * 4, stream);
    hipMemsetAsync(cnt,  0, N_NODES * 4, stream);
    hipMemsetAsync(cnt2, 0, C_CL * 4, stream);

    // ---- y = x @ W_conv[:, 16:144]   (only h-columns survive to outputs)
    mm128<<<(N_NODES * 32) / 256, 256, 0, stream>>>(x, 128, Wconv, 144, 16, y, N_NODES);

    // ---- CSR over dst
    hist_idx<<<(N_EDGES + 255) / 256, 256, 0, stream>>>(dstA, N_EDGES, cnt);
    reduce_blk<<<196, 256, 0, stream>>>(cnt, N_NODES, bsum);
    scan_small<<<1, 256, 0, stream>>>(bsum, 196, nullptr);
    scan_offs<<<196, 256, 0, stream>>>(cnt, N_NODES, bsum, offs);
    hipMemcpyAsync(cursors, offs, N_NODES * 4, hipMemcpyDeviceToDevice, stream);
    scatter_ids<<<(N_EDGES + 255) / 256, 256, 0, stream>>>(dstA, N_EDGES, cursors, eids);

    // ---- h = seg_mean(y[src] + ea@Wce[:,16:], dst)
    gather_h<<<N_NODES / 4, 256, 0, stream>>>(y, ea, offs, cnt, eids, Wce, h);

    // ---- hW = h @ W_gather  (into y's buffer)
    mm128<<<(N_NODES * 32) / 256, 256, 0, stream>>>(h, 128, Wg, 128, 0, hW, N_NODES);

    // ---- CSR over clusters (100k bloom entries, b>>1 = node)
    hist_idx<<<(NK + 255) / 256, 256, 0, stream>>>(clu, NK, cnt2);
    reduce_blk<<<98, 256, 0, stream>>>(cnt2, C_CL, bsum);
    scan_small<<<1, 256, 0, stream>>>(bsum, 98, nullptr);
    scan_offs<<<98, 256, 0, stream>>>(cnt2, C_CL, bsum, offs2);
    hipMemcpyAsync(cursors2, offs2, C_CL * 4, hipMemcpyDeviceToDevice, stream);
    scatter_ids<<<(NK + 255) / 256, 256, 0, stream>>>(clu, NK, cursors2, bids);

    // ---- x_new, new_pos (g_attr term sums to ~0 per cluster -> dropped)
    gather_out<<<C_CL / 4, 256, 0, stream>>>(hW, pos, offs2, cnt2, bids, xnew, newpos);

    // ---- pair pipeline: bin by enc>>18, per-chunk LDS bitmap, sorted-unique emission
    pair_hist<<<HIST_BLOCKS, 256, 0, stream>>>(dstA, clu, gcnt);
    hipMemcpyAsync(goffs, gcnt, NCHUNK * 4, hipMemcpyDeviceToDevice, stream);
    scan_small<<<1, 256, 0, stream>>>(goffs, NCHUNK, nullptr);
    hipMemcpyAsync(gcur, goffs, NCHUNK * 4, hipMemcpyDeviceToDevice, stream);
    pair_scatter<<<HIST_BLOCKS, 256, 0, stream>>>(dstA, clu, gcur, pbuf);
    chunk_count<<<NCHUNK, 256, 0, stream>>>(pbuf, goffs, gcnt, ucnt);
    hipMemcpyAsync(uoffs, ucnt, NCHUNK * 4, hipMemcpyDeviceToDevice, stream);
    scan_small<<<1, 256, 0, stream>>>(uoffs, NCHUNK, Uptr);
    chunk_emit<<<NCHUNK, 256, 0, stream>>>(pbuf, goffs, gcnt, uoffs, newpos, ei0, ei1, attr);
    tail_zero<<<TOTE / 256, 256, 0, stream>>>(Uptr, ei0, ei1, attr);

    (void)in_sizes; (void)n_in; (void)out_size; (void)ws_size;
}

// Round 4
// 984.433 us; speedup vs baseline: 1.4203x; 1.1448x over previous
//
#include <hip/hip_runtime.h>
#include <hip/hip_bf16.h>
#include <stdint.h>

#define N_NODES   50000
#define N_EDGES   400000
#define NK        100000
#define C_CL      25000
#define TOTE      12800000            // N * 16 * 16 pair slots
#define CHUNK_BITS 18                 // 2^18 enc values per chunk -> 32KB LDS bitmap
#define NCHUNK    2385                // ceil(625e6 / 2^18)
#define HIST_BLOCKS 782               // ceil(N / 64)

// ---------------- fuse weights: W1[128][128] = Wconv[:,16:]@Wg ; W2[3][128] = Wce[:,16:]@Wg
__global__ __launch_bounds__(256) void fuse_w(const float* __restrict__ Wconv, const float* __restrict__ Wce,
                                              const float* __restrict__ Wg,
                                              float* __restrict__ W1, float* __restrict__ W2) {
    int id = blockIdx.x * 256 + threadIdx.x;
    int r = id >> 7, c = id & 127;
    if (r >= 131) return;
    float acc = 0.f;
    if (r < 128) {
        const float* wr = Wconv + r * 144 + 16;
#pragma unroll 8
        for (int j = 0; j < 128; ++j) acc += wr[j] * Wg[j * 128 + c];
        W1[r * 128 + c] = acc;
    } else {
        const float* wr = Wce + (r - 128) * 144 + 16;
#pragma unroll 8
        for (int j = 0; j < 128; ++j) acc += wr[j] * Wg[j * 128 + c];
        W2[(r - 128) * 128 + c] = acc;
    }
}

// ---------------- generic 128-K matmul: out[r][c] = sum_k A[r][k] * B[k][c], c<128
__global__ __launch_bounds__(256) void mm128(const float* __restrict__ A, int lda,
                                             const float* __restrict__ B, int ldb,
                                             float* __restrict__ out, int rows) {
    int t = blockIdx.x * 256 + threadIdx.x;
    int r = t >> 5;
    int c = (t & 31) << 2;
    if (r >= rows) return;
    const float* Ar = A + (size_t)r * lda;
    const float* Bc = B + c;
    float4 acc = make_float4(0.f, 0.f, 0.f, 0.f);
#pragma unroll
    for (int k = 0; k < 128; k += 4) {
        float4 a  = *(const float4*)(Ar + k);
        float4 b0 = *(const float4*)(Bc + (size_t)(k + 0) * ldb);
        float4 b1 = *(const float4*)(Bc + (size_t)(k + 1) * ldb);
        float4 b2 = *(const float4*)(Bc + (size_t)(k + 2) * ldb);
        float4 b3 = *(const float4*)(Bc + (size_t)(k + 3) * ldb);
        acc.x += a.x * b0.x + a.y * b1.x + a.z * b2.x + a.w * b3.x;
        acc.y += a.x * b0.y + a.y * b1.y + a.z * b2.y + a.w * b3.y;
        acc.z += a.x * b0.z + a.y * b1.z + a.z * b2.z + a.w * b3.z;
        acc.w += a.x * b0.w + a.y * b1.w + a.z * b2.w + a.w * b3.w;
    }
    *(float4*)(out + (size_t)r * 128 + c) = acc;
}

// ---------------- histograms
__global__ __launch_bounds__(256) void hist_idx(const int* __restrict__ idx, int n, int* __restrict__ cnt) {
    int i = blockIdx.x * 256 + threadIdx.x;
    if (i < n) atomicAdd(&cnt[idx[i]], 1);
}

// ---------------- per-block sum (256 elems/block)
__global__ __launch_bounds__(256) void reduce_blk(const int* __restrict__ v, int n, int* __restrict__ bsum) {
    __shared__ int s[256];
    int t = threadIdx.x;
    int i = blockIdx.x * 256 + t;
    s[t] = (i < n) ? v[i] : 0;
    __syncthreads();
    for (int o = 128; o > 0; o >>= 1) { if (t < o) s[t] += s[t + o]; __syncthreads(); }
    if (t == 0) bsum[blockIdx.x] = s[0];
}

// ---------------- single-block exclusive scan (in place), optional grand total out
__global__ __launch_bounds__(256) void scan_small(int* data, int n, int* total_out) {
    __shared__ int s[256];
    __shared__ int carry;
    int t = threadIdx.x;
    if (t == 0) carry = 0;
    __syncthreads();
    for (int base = 0; base < n; base += 256) {
        int i = base + t;
        int v = (i < n) ? data[i] : 0;
        s[t] = v;
        __syncthreads();
        for (int o = 1; o < 256; o <<= 1) {
            int x = (t >= o) ? s[t - o] : 0;
            __syncthreads();
            s[t] += x;
            __syncthreads();
        }
        int inc = s[t];
        int tot = s[255];
        int cy  = carry;
        __syncthreads();
        if (i < n) data[i] = cy + inc - v;   // exclusive
        if (t == 0) carry = cy + tot;
        __syncthreads();
    }
    if (t == 0 && total_out) *total_out = carry;
}

// ---------------- final exclusive offsets: offs[i] = bscan[blk] + local exclusive prefix
__global__ __launch_bounds__(256) void scan_offs(const int* __restrict__ cnt, int n,
                                                 const int* __restrict__ bscan, int* __restrict__ offs) {
    __shared__ int s[256];
    int t = threadIdx.x;
    int i = blockIdx.x * 256 + t;
    int v = (i < n) ? cnt[i] : 0;
    s[t] = v;
    __syncthreads();
    for (int o = 1; o < 256; o <<= 1) {
        int x = (t >= o) ? s[t - o] : 0;
        __syncthreads();
        s[t] += x;
        __syncthreads();
    }
    if (i < n) offs[i] = bscan[blockIdx.x] + s[t] - v;
}

// ---------------- scatter indices into CSR lists
__global__ __launch_bounds__(256) void scatter_ids(const int* __restrict__ idx, int n,
                                                   int* __restrict__ cursors, int* __restrict__ ids) {
    int i = blockIdx.x * 256 + threadIdx.x;
    if (i < n) {
        int p = atomicAdd(&cursors[idx[i]], 1);
        ids[p] = i;
    }
}

// ---------------- per-dst-node gather: hW[n] = (sum yW[src] + (sum ea) @ W2) / max(cnt,1)
__global__ __launch_bounds__(256) void gather_hW(const float* __restrict__ yW, const float* __restrict__ ea,
                                                 const int* __restrict__ offs, const int* __restrict__ cnt,
                                                 const int* __restrict__ eids, const float* __restrict__ W2,
                                                 float* __restrict__ hW) {
    int l = threadIdx.x & 63;
    int n = blockIdx.x * 4 + (threadIdx.x >> 6);
    int off = offs[n], m = cnt[n];
    float ax = 0.f, ay = 0.f, ae = 0.f;
    for (int i = 0; i < m; ++i) {
        int e = eids[off + i];
        int s = e >> 3;                                   // src = e / DEG
        float2 v = *(const float2*)(yW + (size_t)s * 128 + 2 * l);
        ax += v.x; ay += v.y;
        if (l < 3) ae += ea[(size_t)e * 3 + l];
    }
    float e0 = __shfl(ae, 0), e1 = __shfl(ae, 1), e2 = __shfl(ae, 2);
    float inv = 1.f / (float)(m > 0 ? m : 1);
    int c0 = 2 * l, c1 = 2 * l + 1;
    float h0 = (ax + e0 * W2[c0] + e1 * W2[128 + c0] + e2 * W2[256 + c0]) * inv;
    float h1 = (ay + e0 * W2[c1] + e1 * W2[128 + c1] + e2 * W2[256 + c1]) * inv;
    *(float2*)(hW + (size_t)n * 128 + 2 * l) = make_float2(h0, h1);
}

// ---------------- per-cluster gather: x_new[c] = sum hW[b>>1]/max(cnt,1); new_pos[c] = sum pos[b>>1]/max(cnt,1)
__global__ __launch_bounds__(256) void gather_out(const float* __restrict__ hW, const float* __restrict__ pos,
                                                  const int* __restrict__ offs2, const int* __restrict__ cnt2,
                                                  const int* __restrict__ bids,
                                                  float* __restrict__ xnew, float* __restrict__ newpos) {
    int l = threadIdx.x & 63;
    int c = blockIdx.x * 4 + (threadIdx.x >> 6);
    int off = offs2[c], m = cnt2[c];
    float ax = 0.f, ay = 0.f, ap = 0.f;
    for (int i = 0; i < m; ++i) {
        int b  = bids[off + i];
        int nd = b >> 1;
        float2 v = *(const float2*)(hW + (size_t)nd * 128 + 2 * l);
        ax += v.x; ay += v.y;
        if (l < 3) ap += pos[(size_t)nd * 3 + l];
    }
    float inv = 1.f / (float)(m > 0 ? m : 1);
    *(float2*)(xnew + (size_t)c * 128 + 2 * l) = make_float2(ax * inv, ay * inv);
    if (l < 3) newpos[(size_t)c * 3 + l] = ap * inv;
}

// ---------------- pass 1: per-WG LDS histogram of pair chunks (64 nodes/WG)
__global__ __launch_bounds__(256) void pair_hist(const int* __restrict__ dstA, const int* __restrict__ clu,
                                                 int* __restrict__ gcnt) {
    __shared__ int cb[64][16];
    __shared__ int hist[NCHUNK];
    int t = threadIdx.x;
    int n0 = blockIdx.x * 64;
    int nvalid = N_NODES - n0; if (nvalid > 64) nvalid = 64;
    for (int i = t; i < NCHUNK; i += 256) hist[i] = 0;
    for (int i = t; i < 1024; i += 256) {
        int ln = i >> 4, j = i & 15;
        if (ln < nvalid) {
            int d = dstA[(n0 + ln) * 8 + (j >> 1)];
            cb[ln][j] = clu[d * 2 + (j & 1)];
        }
    }
    __syncthreads();
#pragma unroll 4
    for (int q = 0; q < 64; ++q) {
        int idx = t * 64 + q;
        int ln = idx >> 8, p = idx & 255;
        if (ln < nvalid) {
            unsigned enc = (unsigned)cb[ln][p >> 4] * 25000u + (unsigned)cb[ln][p & 15];
            atomicAdd(&hist[enc >> CHUNK_BITS], 1);
        }
    }
    __syncthreads();
    for (int i = t; i < NCHUNK; i += 256) { int h = hist[i]; if (h) atomicAdd(&gcnt[i], h); }
}

// ---------------- pass 2: two-level scatter of enc values into chunk-ordered buffer
__global__ __launch_bounds__(256) void pair_scatter(const int* __restrict__ dstA, const int* __restrict__ clu,
                                                    int* __restrict__ gcur, unsigned* __restrict__ pbuf) {
    __shared__ int cb[64][16];
    __shared__ int hist[NCHUNK];
    __shared__ int lcur[NCHUNK];
    int t = threadIdx.x;
    int n0 = blockIdx.x * 64;
    int nvalid = N_NODES - n0; if (nvalid > 64) nvalid = 64;
    for (int i = t; i < NCHUNK; i += 256) hist[i] = 0;
    for (int i = t; i < 1024; i += 256) {
        int ln = i >> 4, j = i & 15;
        if (ln < nvalid) {
            int d = dstA[(n0 + ln) * 8 + (j >> 1)];
            cb[ln][j] = clu[d * 2 + (j & 1)];
        }
    }
    __syncthreads();
#pragma unroll 4
    for (int q = 0; q < 64; ++q) {
        int idx = t * 64 + q;
        int ln = idx >> 8, p = idx & 255;
        if (ln < nvalid) {
            unsigned enc = (unsigned)cb[ln][p >> 4] * 25000u + (unsigned)cb[ln][p & 15];
            atomicAdd(&hist[enc >> CHUNK_BITS], 1);
        }
    }
    __syncthreads();
    for (int i = t; i < NCHUNK; i += 256) { int h = hist[i]; if (h) lcur[i] = atomicAdd(&gcur[i], h); }
    __syncthreads();
#pragma unroll 4
    for (int q = 0; q < 64; ++q) {
        int idx = t * 64 + q;
        int ln = idx >> 8, p = idx & 255;
        if (ln < nvalid) {
            unsigned enc = (unsigned)cb[ln][p >> 4] * 25000u + (unsigned)cb[ln][p & 15];
            int pos = atomicAdd(&lcur[enc >> CHUNK_BITS], 1);
            pbuf[pos] = enc;
        }
    }
}

// ---------------- pass 3: per-chunk LDS bitmap -> IN-PLACE sorted-unique compaction + count
// Reads of pbuf[off..off+m) all complete before the barrier; compacted writes (<= m)
// go back into the same region. Word ownership interleaved (bank = t%32, conflict-free).
__global__ __launch_bounds__(256) void chunk_compact(unsigned* __restrict__ pbuf,
                                                     const int* __restrict__ goffs, const int* __restrict__ gcnt,
                                                     int* __restrict__ ucnt) {
    __shared__ unsigned bm[8192];
    __shared__ int wsum[32][4];
    int t = threadIdx.x, c = blockIdx.x;
    int lane = t & 63, wid = t >> 6;
    for (int i = t; i < 8192; i += 256) bm[i] = 0;
    __syncthreads();
    int off = goffs[c], m = gcnt[c];
    unsigned basee = (unsigned)c << CHUNK_BITS;
    for (int i = t; i < m; i += 256) {
        unsigned e = pbuf[off + i] - basee;
        atomicOr(&bm[e >> 5], 1u << (e & 31));
    }
    __syncthreads();
    int carry = 0;
    for (int g = 0; g < 32; ++g) {
        unsigned word = bm[g * 256 + t];
        int pc = __popc(word);
        int incl = pc;
#pragma unroll
        for (int o = 1; o < 64; o <<= 1) {
            int v = __shfl_up(incl, o, 64);
            if (lane >= o) incl += v;
        }
        if (lane == 63) wsum[g][wid] = incl;
        __syncthreads();
        int w0 = wsum[g][0], w1 = wsum[g][1], w2 = wsum[g][2], w3 = wsum[g][3];
        int wpre = (wid > 0 ? w0 : 0) + (wid > 1 ? w1 : 0) + (wid > 2 ? w2 : 0);
        int rank = off + carry + wpre + incl - pc;
        carry += w0 + w1 + w2 + w3;
        unsigned wbase = basee + (((unsigned)(g * 256 + t)) << 5);
        while (word) {
            int b = __ffs(word) - 1;
            word &= word - 1;
            pbuf[rank++] = wbase + (unsigned)b;
        }
    }
    if (t == 0) ucnt[c] = carry;
}

// ---------------- pass 4: dense expand of compacted encs -> ei0/ei1/attr (fully coalesced)
__global__ __launch_bounds__(256) void expand(const unsigned* __restrict__ pbuf,
                                              const int* __restrict__ goffs, const int* __restrict__ ucnt,
                                              const int* __restrict__ uoffs, const float* __restrict__ newpos,
                                              float* __restrict__ ei0, float* __restrict__ ei1,
                                              float* __restrict__ attr) {
    int t = threadIdx.x, c = blockIdx.x;
    int src = goffs[c], dst = uoffs[c], n = ucnt[c];
    for (int j = t; j < n; j += 256) {
        unsigned v  = pbuf[src + j];
        unsigned ns = v / 25000u;
        unsigned nd = v - ns * 25000u;
        int o = dst + j;
        ei0[o] = (float)ns;
        ei1[o] = (float)nd;
        float dx = newpos[nd * 3 + 0] - newpos[ns * 3 + 0];
        float dy = newpos[nd * 3 + 1] - newpos[ns * 3 + 1];
        float dz = newpos[nd * 3 + 2] - newpos[ns * 3 + 2];
        attr[(size_t)3 * o + 0] = dx;
        attr[(size_t)3 * o + 1] = dy;
        attr[(size_t)3 * o + 2] = dz;
    }
}

// ---------------- zero the padded tail (slots >= U)
__global__ __launch_bounds__(256) void tail_zero(const int* __restrict__ Uptr,
                                                 float* __restrict__ ei0, float* __restrict__ ei1,
                                                 float* __restrict__ attr) {
    int i = blockIdx.x * 256 + threadIdx.x;
    if (i >= TOTE) return;
    if (i >= *Uptr) {
        ei0[i] = 0.f;
        ei1[i] = 0.f;
        attr[(size_t)3 * i + 0] = 0.f;
        attr[(size_t)3 * i + 1] = 0.f;
        attr[(size_t)3 * i + 2] = 0.f;
    }
}

extern "C" void kernel_launch(void* const* d_in, const int* in_sizes, int n_in,
                              void* d_out, int out_size, void* d_ws, size_t ws_size,
                              hipStream_t stream) {
    const float* x     = (const float*)d_in[0];
    const float* pos   = (const float*)d_in[1];
    const int*   dstA  = (const int*)d_in[2] + N_EDGES;   // edge_index row 1
    const float* ea    = (const float*)d_in[3];
    const int*   clu   = (const int*)d_in[5];
    const float* Wconv = (const float*)d_in[6];           // (128,144)
    const float* Wce   = (const float*)d_in[7];           // (3,144)
    const float* Wg    = (const float*)d_in[9];           // (128,128)

    // ---- output layout (floats): x_new | new_pos | ei0 | ei1 | attr
    float* out_f  = (float*)d_out;
    float* xnew   = out_f;                       // 3,200,000
    float* newpos = out_f + 3200000;             // 75,000
    float* ei0    = out_f + 3275000;             // 12,800,000
    float* ei1    = out_f + 16075000;            // 12,800,000
    float* attr   = out_f + 28875000;            // 38,400,000
    // scratch aliased into attr region (dead before expand/tail write attr)
    float* yW     = attr;                        // 6,400,000 floats (N x 128)
    float* hW     = attr + 6400000;              // 6,400,000 floats

    // ---- workspace layout
    uint8_t* w8 = (uint8_t*)d_ws;
    unsigned* pbuf = (unsigned*)(w8);                         // 51,200,000 B
    int* cnt       = (int*)(w8 + 51200000);                   // 200,000
    int* offs      = (int*)(w8 + 51400000);                   // 200,000
    int* cursors   = (int*)(w8 + 51600000);                   // 200,000
    int* eids      = (int*)(w8 + 51800000);                   // 1,600,000
    int* cnt2      = (int*)(w8 + 53400000);                   // 100,000
    int* offs2     = (int*)(w8 + 53500000);                   // 100,000
    int* cursors2  = (int*)(w8 + 53600000);                   // 100,000
    int* bids      = (int*)(w8 + 53700000);                   // 400,000
    int* bsum      = (int*)(w8 + 54100000);                   // 20,480
    int* gcnt      = (int*)(w8 + 54120480);                   // 9,540
    int* goffs     = (int*)(w8 + 54130020);                   // 9,540
    int* gcur      = (int*)(w8 + 54139560);                   // 9,540
    int* ucnt      = (int*)(w8 + 54149100);                   // 9,540
    int* uoffs     = (int*)(w8 + 54158640);                   // 9,540
    int* Uptr      = (int*)(w8 + 54168180);                   // 4
    float* W1      = (float*)(w8 + 54200000);                 // 65,536 B
    float* W2      = (float*)(w8 + 54265536);                 // 1,536 B

    // ---- zero-init
    hipMemsetAsync(gcnt, 0, NCHUNK * 4, stream);
    hipMemsetAsync(cnt,  0, N_NODES * 4, stream);
    hipMemsetAsync(cnt2, 0, C_CL * 4, stream);

    // ---- W1 = Wconv[:,16:]@Wg, W2 = Wce[:,16:]@Wg  (mean-then-linear == linear-then-mean)
    fuse_w<<<66, 256, 0, stream>>>(Wconv, Wce, Wg, W1, W2);

    // ---- yW = x @ W1
    mm128<<<(N_NODES * 32) / 256, 256, 0, stream>>>(x, 128, W1, 128, yW, N_NODES);

    // ---- CSR over dst
    hist_idx<<<(N_EDGES + 255) / 256, 256, 0, stream>>>(dstA, N_EDGES, cnt);
    reduce_blk<<<196, 256, 0, stream>>>(cnt, N_NODES, bsum);
    scan_small<<<1, 256, 0, stream>>>(bsum, 196, nullptr);
    scan_offs<<<196, 256, 0, stream>>>(cnt, N_NODES, bsum, offs);
    hipMemcpyAsync(cursors, offs, N_NODES * 4, hipMemcpyDeviceToDevice, stream);
    scatter_ids<<<(N_EDGES + 255) / 256, 256, 0, stream>>>(dstA, N_EDGES, cursors, eids);

    // ---- hW = seg_mean(yW[src] + ea@W2, dst)
    gather_hW<<<N_NODES / 4, 256, 0, stream>>>(yW, ea, offs, cnt, eids, W2, hW);

    // ---- CSR over clusters (100k bloom entries, b>>1 = node)
    hist_idx<<<(NK + 255) / 256, 256, 0, stream>>>(clu, NK, cnt2);
    reduce_blk<<<98, 256, 0, stream>>>(cnt2, C_CL, bsum);
    scan_small<<<1, 256, 0, stream>>>(bsum, 98, nullptr);
    scan_offs<<<98, 256, 0, stream>>>(cnt2, C_CL, bsum, offs2);
    hipMemcpyAsync(cursors2, offs2, C_CL * 4, hipMemcpyDeviceToDevice, stream);
    scatter_ids<<<(NK + 255) / 256, 256, 0, stream>>>(clu, NK, cursors2, bids);

    // ---- x_new, new_pos (g_attr term sums to ~0 per cluster -> dropped)
    gather_out<<<C_CL / 4, 256, 0, stream>>>(hW, pos, offs2, cnt2, bids, xnew, newpos);

    // ---- pair pipeline: bin by enc>>18, per-chunk LDS bitmap compaction, dense expand
    pair_hist<<<HIST_BLOCKS, 256, 0, stream>>>(dstA, clu, gcnt);
    hipMemcpyAsync(goffs, gcnt, NCHUNK * 4, hipMemcpyDeviceToDevice, stream);
    scan_small<<<1, 256, 0, stream>>>(goffs, NCHUNK, nullptr);
    hipMemcpyAsync(gcur, goffs, NCHUNK * 4, hipMemcpyDeviceToDevice, stream);
    pair_scatter<<<HIST_BLOCKS, 256, 0, stream>>>(dstA, clu, gcur, pbuf);
    chunk_compact<<<NCHUNK, 256, 0, stream>>>(pbuf, goffs, gcnt, ucnt);
    hipMemcpyAsync(uoffs, ucnt, NCHUNK * 4, hipMemcpyDeviceToDevice, stream);
    scan_small<<<1, 256, 0, stream>>>(uoffs, NCHUNK, Uptr);
    expand<<<NCHUNK, 256, 0, stream>>>(pbuf, goffs, ucnt, uoffs, newpos, ei0, ei1, attr);
    tail_zero<<<TOTE / 256, 256, 0, stream>>>(Uptr, ei0, ei1, attr);

    (void)in_sizes; (void)n_in; (void)out_size; (void)ws_size;
}